// Round 7
// baseline (130.187 us; speedup 1.0000x reference)
//
#include <hip/hip_runtime.h>

#define NLEV 8
#define PTS_PER_BLOCK 64
#define ROW_F 51   // 3 + 6*NLEV

// 16B load at 8B-aligned address (two consecutive 8B table entries)
typedef unsigned int u4a8 __attribute__((ext_vector_type(4), aligned(8)));

// ---------------------------------------------------------------------------
// Phase repack: data (T anchors x 3 f32) -> tab (T x 8B entries).
// Entry i = anchor i's 3 components as u16 phases (revolutions*65536),
// phase = fract(val * 2^l / 2pi), l = level owning anchor i.
// ---------------------------------------------------------------------------
__global__ __launch_bounds__(256) void phase_repack8(
    const float* __restrict__ data,
    const int*   __restrict__ level_offsets,
    uint2* __restrict__ tab, int T)
{
    __shared__ float sv[256 * 3];
    __shared__ int   soff[NLEV];
    const int tid  = threadIdx.x;
    const int base = blockIdx.x * 256;

    if (tid < NLEV) soff[tid] = level_offsets[tid];
    for (int k = tid; k < 256 * 3; k += 256) {
        const int gi = base * 3 + k;
        sv[k] = (gi < T * 3) ? data[gi] : 0.0f;   // coalesced stream
    }
    __syncthreads();

    const int i = base + tid;
    if (i >= T) return;

    int l = 0;
    #pragma unroll
    for (int j = 1; j < NLEV; ++j) l += (i >= soff[j]) ? 1 : 0;
    const float s = (float)(1 << l) * 0.15915494309189535f;   // freq / 2pi

    unsigned q[3];
    #pragma unroll
    for (int k = 0; k < 3; ++k) {
        float f = sv[tid * 3 + k] * s;
        f -= floorf(f);                             // [0,1) revolutions
        q[k] = ((unsigned)(f * 65536.0f + 0.5f)) & 0xffffu;  // 65536 wraps to 0
    }
    tab[i] = make_uint2(q[0] | (q[1] << 16), q[2]);
}

// sin/cos on revolutions in [0,1): pre-reduced domain for HW trans units
__device__ __forceinline__ void sincos_rev(float r, float& sn, float& cs) {
    asm("v_sin_f32 %0, %1" : "=v"(sn) : "v"(r));
    asm("v_cos_f32 %0, %1" : "=v"(cs) : "v"(r));
}

// ---------------------------------------------------------------------------
// Main kernel: 2 (point,level) units per thread, 4 aligned dwordx4 per unit.
// __launch_bounds__(256,4): cap VGPR at 128 so all 8 gathers stay in flight.
// ---------------------------------------------------------------------------
__global__ __launch_bounds__(256, 4) void dagrid_kernel(
    const float* __restrict__ xyz,
    const uint2* __restrict__ tab,
    const float* __restrict__ scales,
    const int*   __restrict__ level_offsets,
    const float* __restrict__ bounds,
    float* __restrict__ out,
    int npts)
{
    __shared__ alignas(16) float sxyz[PTS_PER_BLOCK * 3];
    __shared__ alignas(16) float sres[PTS_PER_BLOCK][ROW_F];

    const int tid = threadIdx.x;
    const int l   = tid & 7;        // level (shared by both units)
    const int p   = tid >> 3;       // local point A: 0..31; point B: p+32
    const int block_base = blockIdx.x * PTS_PER_BLOCK;
    const bool full_block = (block_base + PTS_PER_BLOCK <= npts);

    if (full_block) {
        if (tid < 48)
            ((float4*)sxyz)[tid] = ((const float4*)(xyz + (size_t)block_base * 3))[tid];
    } else if (tid < PTS_PER_BLOCK * 3) {
        const int gi = block_base * 3 + tid;
        sxyz[tid] = (gi < npts * 3) ? xyz[gi] : 0.0f;
    }

    const float scale = scales[l];
    const int   off_l = level_offsets[l];

    const float lox = bounds[0], loy = bounds[1], loz = bounds[2];
    const float hix = bounds[3] - 1e-6f;
    const float hiy = bounds[4] - 1e-6f;
    const float hiz = bounds[5] - 1e-6f;
    const float size = fmaxf(fmaxf(bounds[3] - bounds[0], bounds[4] - bounds[1]),
                             bounds[5] - bounds[2]);
    const float inv_size = 1.0f / size;

    __syncthreads();

    const int nA = block_base + p;
    const int nB = nA + 32;
    const bool actA = (nA < npts);
    const bool actB = (nB < npts);

    const float rxA = sxyz[p * 3 + 0], ryA = sxyz[p * 3 + 1], rzA = sxyz[p * 3 + 2];
    const float rxB = sxyz[(p + 32) * 3 + 0], ryB = sxyz[(p + 32) * 3 + 1],
                rzB = sxyz[(p + 32) * 3 + 2];

    const int r1   = (int)scale + 1;
    const int r1sq = r1 * r1;

    #define ADDR(rx, ry, rz, act, ox, oy, oz, idx)                                \
    {                                                                             \
        const float x = fminf(fmaxf(rx, lox), hix);                               \
        const float y = fminf(fmaxf(ry, loy), hiy);                               \
        const float z = fminf(fmaxf(rz, loz), hiz);                               \
        const float fx = (x - lox) * inv_size * scale;                            \
        const float fy = (y - loy) * inv_size * scale;                            \
        const float fz = (z - loz) * inv_size * scale;                            \
        const float bxf = floorf(fx), byf = floorf(fy), bzf = floorf(fz);         \
        ox = fx - bxf; oy = fy - byf; oz = fz - bzf;                              \
        idx = act ? ((int)bxf * r1sq + (int)byf * r1 + (int)bzf + off_l) : 0;     \
    }
    float oxA, oyA, ozA, oxB, oyB, ozB;
    int idxA, idxB;
    ADDR(rxA, ryA, rzA, actA, oxA, oyA, ozA, idxA)
    ADDR(rxB, ryB, rzB, actB, oxB, oyB, ozB, idxB)
    #undef ADDR

    // ---- gather: 8 x dwordx4 (2 units x 4 corner-pairs)
    const u4a8 tA0 = *(const u4a8*)(tab + idxA);
    const u4a8 tA1 = *(const u4a8*)(tab + idxA + r1);
    const u4a8 tA2 = *(const u4a8*)(tab + idxA + r1sq);
    const u4a8 tA3 = *(const u4a8*)(tab + idxA + r1sq + r1);
    const u4a8 tB0 = *(const u4a8*)(tab + idxB);
    const u4a8 tB1 = *(const u4a8*)(tab + idxB + r1);
    const u4a8 tB2 = *(const u4a8*)(tab + idxB + r1sq);
    const u4a8 tB3 = *(const u4a8*)(tab + idxB + r1sq + r1);

    unsigned eA0x = tA0.x, eA0y = tA0.y, eA0z = tA0.z, eA0w = tA0.w;
    unsigned eA1x = tA1.x, eA1y = tA1.y, eA1z = tA1.z, eA1w = tA1.w;
    unsigned eA2x = tA2.x, eA2y = tA2.y, eA2z = tA2.z, eA2w = tA2.w;
    unsigned eA3x = tA3.x, eA3y = tA3.y, eA3z = tA3.z, eA3w = tA3.w;
    unsigned eB0x = tB0.x, eB0y = tB0.y, eB0z = tB0.z, eB0w = tB0.w;
    unsigned eB1x = tB1.x, eB1y = tB1.y, eB1z = tB1.z, eB1w = tB1.w;
    unsigned eB2x = tB2.x, eB2y = tB2.y, eB2z = tB2.z, eB2w = tB2.w;
    unsigned eB3x = tB3.x, eB3y = tB3.y, eB3z = tB3.z, eB3w = tB3.w;

    // ---- MLP pin: no compute may be scheduled before all 8 loads are issued.
    // asm #1 pins the A batch; asm #2 pins the B batch AND rewrites the A .x
    // components, so every A-consuming instruction also depends on asm #2.
    asm volatile("" : "+v"(eA0x), "+v"(eA0y), "+v"(eA0z), "+v"(eA0w),
                      "+v"(eA1x), "+v"(eA1y), "+v"(eA1z), "+v"(eA1w),
                      "+v"(eA2x), "+v"(eA2y), "+v"(eA2z), "+v"(eA2w),
                      "+v"(eA3x), "+v"(eA3y), "+v"(eA3z), "+v"(eA3w));
    asm volatile("" : "+v"(eB0x), "+v"(eB0y), "+v"(eB0z), "+v"(eB0w),
                      "+v"(eB1x), "+v"(eB1y), "+v"(eB1z), "+v"(eB1w),
                      "+v"(eB2x), "+v"(eB2y), "+v"(eB2z), "+v"(eB2w),
                      "+v"(eB3x), "+v"(eB3y), "+v"(eB3z), "+v"(eB3w),
                      "+v"(eA0x), "+v"(eA1x), "+v"(eA2x), "+v"(eA3x));

    const float K = 1.0f / 65536.0f;   // u16 phase -> revolutions

    // e = [p0x|p0y<<16, p0z, p1x|p1y<<16, p1z] (high halves of y/w are zero)
    #define PAIRE(ex, ey, ez, ew, WXY, oz_, wz0_, a0, a1, a2, a3, a4, a5)         \
    {                                                                             \
        const float w0 = (WXY) * (wz0_);                                          \
        const float w1 = (WXY) * (oz_);                                           \
        float sn, cs;                                                             \
        sincos_rev((float)(ex & 0xffffu) * K, sn, cs); a0 += w0*sn; a3 += w0*cs;  \
        sincos_rev((float)(ex >> 16)     * K, sn, cs); a1 += w0*sn; a4 += w0*cs;  \
        sincos_rev((float)(ey)           * K, sn, cs); a2 += w0*sn; a5 += w0*cs;  \
        sincos_rev((float)(ez & 0xffffu) * K, sn, cs); a0 += w1*sn; a3 += w1*cs;  \
        sincos_rev((float)(ez >> 16)     * K, sn, cs); a1 += w1*sn; a4 += w1*cs;  \
        sincos_rev((float)(ew)           * K, sn, cs); a2 += w1*sn; a5 += w1*cs;  \
    }

    float a0 = 0.f, a1 = 0.f, a2 = 0.f, a3 = 0.f, a4 = 0.f, a5 = 0.f;
    {
        const float wz0 = 1.0f - ozA;
        const float wx0 = 1.0f - oxA, wy0 = 1.0f - oyA;
        PAIRE(eA0x, eA0y, eA0z, eA0w, wx0 * wy0, ozA, wz0, a0, a1, a2, a3, a4, a5)
        PAIRE(eA1x, eA1y, eA1z, eA1w, wx0 * oyA, ozA, wz0, a0, a1, a2, a3, a4, a5)
        PAIRE(eA2x, eA2y, eA2z, eA2w, oxA * wy0, ozA, wz0, a0, a1, a2, a3, a4, a5)
        PAIRE(eA3x, eA3y, eA3z, eA3w, oxA * oyA, ozA, wz0, a0, a1, a2, a3, a4, a5)
    }
    float b0 = 0.f, b1 = 0.f, b2 = 0.f, b3 = 0.f, b4 = 0.f, b5 = 0.f;
    {
        const float wz0 = 1.0f - ozB;
        const float wx0 = 1.0f - oxB, wy0 = 1.0f - oyB;
        PAIRE(eB0x, eB0y, eB0z, eB0w, wx0 * wy0, ozB, wz0, b0, b1, b2, b3, b4, b5)
        PAIRE(eB1x, eB1y, eB1z, eB1w, wx0 * oyB, ozB, wz0, b0, b1, b2, b3, b4, b5)
        PAIRE(eB2x, eB2y, eB2z, eB2w, oxB * wy0, ozB, wz0, b0, b1, b2, b3, b4, b5)
        PAIRE(eB3x, eB3y, eB3z, eB3w, oxB * oyB, ozB, wz0, b0, b1, b2, b3, b4, b5)
    }
    #undef PAIRE

    {
        const int c = 3 + l * 6;
        float* rowA = sres[p];
        rowA[c + 0] = a0; rowA[c + 1] = a1; rowA[c + 2] = a2;
        rowA[c + 3] = a3; rowA[c + 4] = a4; rowA[c + 5] = a5;
        float* rowB = sres[p + 32];
        rowB[c + 0] = b0; rowB[c + 1] = b1; rowB[c + 2] = b2;
        rowB[c + 3] = b3; rowB[c + 4] = b4; rowB[c + 5] = b5;
        if (l == 0) {
            rowA[0] = rxA; rowA[1] = ryA; rowA[2] = rzA;
            rowB[0] = rxB; rowB[1] = ryB; rowB[2] = rzB;
        }
    }
    __syncthreads();

    // coalesced write: 64*51 = 3264 floats = 816 float4 per block (16B aligned)
    if (full_block) {
        const float4* flat4 = (const float4*)&sres[0][0];
        float4* ob4 = (float4*)(out + (size_t)block_base * ROW_F);
        for (int i = tid; i < (PTS_PER_BLOCK * ROW_F) / 4; i += 256)
            ob4[i] = flat4[i];
    } else {
        const float* flat = &sres[0][0];
        float* ob = out + (size_t)block_base * ROW_F;
        const int lim = npts * ROW_F - block_base * ROW_F;
        for (int i = tid; i < PTS_PER_BLOCK * ROW_F; i += 256)
            if (i < lim) ob[i] = flat[i];
    }
}

// ---------------------------------------------------------------------------
// Fallback (ws too small): direct fp32 gather (x4u + x2u), known-good (R3).
// ---------------------------------------------------------------------------
typedef float f4u __attribute__((ext_vector_type(4), aligned(4)));
typedef float f2u __attribute__((ext_vector_type(2), aligned(4)));

__global__ __launch_bounds__(256) void dagrid_kernel_direct(
    const float* __restrict__ xyz,
    const float* __restrict__ data,
    const float* __restrict__ scales,
    const int*   __restrict__ level_offsets,
    const float* __restrict__ bounds,
    float* __restrict__ out,
    int npts)
{
    __shared__ alignas(16) float sxyz[32 * 3];
    __shared__ alignas(16) float sres[32][ROW_F];

    const int tid = threadIdx.x;
    const int l   = tid & 7;
    const int p   = tid >> 3;
    const int block_base = blockIdx.x * 32;

    if (tid < 32 * 3) {
        const int gi = block_base * 3 + tid;
        sxyz[tid] = (gi < npts * 3) ? xyz[gi] : 0.0f;
    }
    const float scale = scales[l];
    const int   off_l = level_offsets[l];
    const float lox = bounds[0], loy = bounds[1], loz = bounds[2];
    const float hix = bounds[3] - 1e-6f;
    const float hiy = bounds[4] - 1e-6f;
    const float hiz = bounds[5] - 1e-6f;
    const float size = fmaxf(fmaxf(bounds[3] - bounds[0], bounds[4] - bounds[1]),
                             bounds[5] - bounds[2]);
    const float inv_size = 1.0f / size;
    __syncthreads();

    const int n = block_base + p;
    const bool active = (n < npts);
    const float rx = sxyz[p * 3 + 0];
    const float ry = sxyz[p * 3 + 1];
    const float rz = sxyz[p * 3 + 2];
    float acc0 = 0.f, acc1 = 0.f, acc2 = 0.f, acc3 = 0.f, acc4 = 0.f, acc5 = 0.f;

    if (active) {
        const float x = fminf(fmaxf(rx, lox), hix);
        const float y = fminf(fmaxf(ry, loy), hiy);
        const float z = fminf(fmaxf(rz, loz), hiz);
        const float xn = (x - lox) * inv_size;
        const float yn = (y - loy) * inv_size;
        const float zn = (z - loz) * inv_size;
        const int r1 = (int)scale + 1;
        const int r1sq = r1 * r1;
        const float fx = xn * scale, fy = yn * scale, fz = zn * scale;
        const float bxf = floorf(fx), byf = floorf(fy), bzf = floorf(fz);
        const float ox = fx - bxf, oy = fy - byf, oz = fz - bzf;
        const int i000 = (int)bxf * r1sq + (int)byf * r1 + (int)bzf + off_l;
        const float* p0 = data + 3 * (size_t)i000;
        const float* p1 = p0 + 3 * r1;
        const float* p2 = p0 + 3 * r1sq;
        const float* p3 = p2 + 3 * r1;
        const f4u q0 = *(const f4u*)p0;  const f2u g0 = *(const f2u*)(p0 + 4);
        const f4u q1 = *(const f4u*)p1;  const f2u g1 = *(const f2u*)(p1 + 4);
        const f4u q2 = *(const f4u*)p2;  const f2u g2 = *(const f2u*)(p2 + 4);
        const f4u q3 = *(const f4u*)p3;  const f2u g3 = *(const f2u*)(p3 + 4);
        const float freq = (float)(1 << l);
        const float wz0 = 1.0f - oz;
        const float wx1 = ox, wx0 = 1.0f - ox;
        const float wy1 = oy, wy0 = 1.0f - oy;
        float sn, cs;
        #define PAIR(a, b, WXY)                                                   \
        {                                                                         \
            const float w0 = (WXY) * wz0;                                         \
            const float w1 = (WXY) * oz;                                          \
            __sincosf(a.x * freq, &sn, &cs); acc0 += w0 * sn; acc3 += w0 * cs;    \
            __sincosf(a.y * freq, &sn, &cs); acc1 += w0 * sn; acc4 += w0 * cs;    \
            __sincosf(a.z * freq, &sn, &cs); acc2 += w0 * sn; acc5 += w0 * cs;    \
            __sincosf(a.w * freq, &sn, &cs); acc0 += w1 * sn; acc3 += w1 * cs;    \
            __sincosf(b.x * freq, &sn, &cs); acc1 += w1 * sn; acc4 += w1 * cs;    \
            __sincosf(b.y * freq, &sn, &cs); acc2 += w1 * sn; acc5 += w1 * cs;    \
        }
        PAIR(q0, g0, wx0 * wy0)
        PAIR(q1, g1, wx0 * wy1)
        PAIR(q2, g2, wx1 * wy0)
        PAIR(q3, g3, wx1 * wy1)
        #undef PAIR
    }
    {
        float* row = sres[p];
        const int c = 3 + l * 6;
        row[c + 0] = acc0; row[c + 1] = acc1; row[c + 2] = acc2;
        row[c + 3] = acc3; row[c + 4] = acc4; row[c + 5] = acc5;
        if (l == 0) { row[0] = rx; row[1] = ry; row[2] = rz; }
    }
    __syncthreads();
    {
        const float* flat = &sres[0][0];
        float* ob = out + (size_t)block_base * ROW_F;
        const int lim = npts * ROW_F - block_base * ROW_F;
        for (int i = tid; i < 32 * ROW_F; i += 256)
            if (i < lim) ob[i] = flat[i];
    }
}

extern "C" void kernel_launch(void* const* d_in, const int* in_sizes, int n_in,
                              void* d_out, int out_size, void* d_ws, size_t ws_size,
                              hipStream_t stream) {
    const float* xyz           = (const float*)d_in[0];
    const float* data          = (const float*)d_in[1];
    const float* scales        = (const float*)d_in[2];
    const int*   level_offsets = (const int*)d_in[3];
    const float* bounds        = (const float*)d_in[4];
    float* out = (float*)d_out;

    const int npts = in_sizes[0] / 3;
    const int T    = in_sizes[1] / 3;

    const size_t ws_needed = (size_t)T * sizeof(uint2);
    if (d_ws != nullptr && ws_size >= ws_needed) {
        uint2* tab = (uint2*)d_ws;
        phase_repack8<<<(T + 255) / 256, 256, 0, stream>>>(data, level_offsets, tab, T);
        const int nblocks = (npts + PTS_PER_BLOCK - 1) / PTS_PER_BLOCK;
        dagrid_kernel<<<nblocks, 256, 0, stream>>>(xyz, tab, scales, level_offsets,
                                                   bounds, out, npts);
    } else {
        const int nblocks = (npts + 31) / 32;
        dagrid_kernel_direct<<<nblocks, 256, 0, stream>>>(xyz, data, scales,
                                                          level_offsets, bounds,
                                                          out, npts);
    }
}

// Round 8
// 130.095 us; speedup vs baseline: 1.0007x; 1.0007x over previous
//
#include <hip/hip_runtime.h>

#define NLEV 8
#define PTS_PER_BLOCK 64
#define ROW_F 51   // 3 + 6*NLEV

typedef unsigned int u32x4 __attribute__((ext_vector_type(4)));

// ---------------------------------------------------------------------------
// Phase repack: data (T anchors x 3 f32) -> tab (T x 8B entries).
// Entry i = anchor i's 3 components as u16 phases (revolutions*65536),
// phase = fract(val * 2^l / 2pi), l = level owning anchor i.
// ---------------------------------------------------------------------------
__global__ __launch_bounds__(256) void phase_repack8(
    const float* __restrict__ data,
    const int*   __restrict__ level_offsets,
    uint2* __restrict__ tab, int T)
{
    __shared__ float sv[256 * 3];
    __shared__ int   soff[NLEV];
    const int tid  = threadIdx.x;
    const int base = blockIdx.x * 256;

    if (tid < NLEV) soff[tid] = level_offsets[tid];
    for (int k = tid; k < 256 * 3; k += 256) {
        const int gi = base * 3 + k;
        sv[k] = (gi < T * 3) ? data[gi] : 0.0f;   // coalesced stream
    }
    __syncthreads();

    const int i = base + tid;
    if (i >= T) return;

    int l = 0;
    #pragma unroll
    for (int j = 1; j < NLEV; ++j) l += (i >= soff[j]) ? 1 : 0;
    const float s = (float)(1 << l) * 0.15915494309189535f;   // freq / 2pi

    unsigned q[3];
    #pragma unroll
    for (int k = 0; k < 3; ++k) {
        float f = sv[tid * 3 + k] * s;
        f -= floorf(f);                             // [0,1) revolutions
        q[k] = ((unsigned)(f * 65536.0f + 0.5f)) & 0xffffu;  // 65536 wraps to 0
    }
    tab[i] = make_uint2(q[0] | (q[1] << 16), q[2]);
}

// sin/cos on revolutions in [0,1): pre-reduced domain for HW trans units
__device__ __forceinline__ void sincos_rev(float r, float& sn, float& cs) {
    asm("v_sin_f32 %0, %1" : "=v"(sn) : "v"(r));
    asm("v_cos_f32 %0, %1" : "=v"(cs) : "v"(r));
}

// ---------------------------------------------------------------------------
// Main kernel: 2 (point,level) units per thread. The 8 corner-pair gathers are
// hand-issued as inline-asm global_load_dwordx4 so the compiler cannot split
// the batch (it did, twice: R6/R7 both kept VGPR=36 and serialized 2 rounds).
// ---------------------------------------------------------------------------
__global__ __launch_bounds__(256, 4) void dagrid_kernel(
    const float* __restrict__ xyz,
    const uint2* __restrict__ tab,
    const float* __restrict__ scales,
    const int*   __restrict__ level_offsets,
    const float* __restrict__ bounds,
    float* __restrict__ out,
    int npts)
{
    __shared__ alignas(16) float sxyz[PTS_PER_BLOCK * 3];
    __shared__ alignas(16) float sres[PTS_PER_BLOCK][ROW_F];

    const int tid = threadIdx.x;
    const int l   = tid & 7;        // level (shared by both units)
    const int p   = tid >> 3;       // local point A: 0..31; point B: p+32
    const int block_base = blockIdx.x * PTS_PER_BLOCK;
    const bool full_block = (block_base + PTS_PER_BLOCK <= npts);

    if (full_block) {
        if (tid < 48)
            ((float4*)sxyz)[tid] = ((const float4*)(xyz + (size_t)block_base * 3))[tid];
    } else if (tid < PTS_PER_BLOCK * 3) {
        const int gi = block_base * 3 + tid;
        sxyz[tid] = (gi < npts * 3) ? xyz[gi] : 0.0f;
    }

    const float scale = scales[l];
    const int   off_l = level_offsets[l];

    const float lox = bounds[0], loy = bounds[1], loz = bounds[2];
    const float hix = bounds[3] - 1e-6f;
    const float hiy = bounds[4] - 1e-6f;
    const float hiz = bounds[5] - 1e-6f;
    const float size = fmaxf(fmaxf(bounds[3] - bounds[0], bounds[4] - bounds[1]),
                             bounds[5] - bounds[2]);
    const float inv_size = 1.0f / size;

    __syncthreads();

    const int nA = block_base + p;
    const int nB = nA + 32;
    const bool actA = (nA < npts);
    const bool actB = (nB < npts);

    const float rxA = sxyz[p * 3 + 0], ryA = sxyz[p * 3 + 1], rzA = sxyz[p * 3 + 2];
    const float rxB = sxyz[(p + 32) * 3 + 0], ryB = sxyz[(p + 32) * 3 + 1],
                rzB = sxyz[(p + 32) * 3 + 2];

    const int r1   = (int)scale + 1;
    const int r1sq = r1 * r1;

    #define ADDR(rx, ry, rz, act, ox, oy, oz, idx)                                \
    {                                                                             \
        const float x = fminf(fmaxf(rx, lox), hix);                               \
        const float y = fminf(fmaxf(ry, loy), hiy);                               \
        const float z = fminf(fmaxf(rz, loz), hiz);                               \
        const float fx = (x - lox) * inv_size * scale;                            \
        const float fy = (y - loy) * inv_size * scale;                            \
        const float fz = (z - loz) * inv_size * scale;                            \
        const float bxf = floorf(fx), byf = floorf(fy), bzf = floorf(fz);         \
        ox = fx - bxf; oy = fy - byf; oz = fz - bzf;                              \
        idx = act ? ((int)bxf * r1sq + (int)byf * r1 + (int)bzf + off_l) : 0;     \
    }
    float oxA, oyA, ozA, oxB, oyB, ozB;
    int idxA, idxB;
    ADDR(rxA, ryA, rzA, actA, oxA, oyA, ozA, idxA)
    ADDR(rxB, ryB, rzB, actB, oxB, oyB, ozB, idxB)
    #undef ADDR

    // ---- gather: 8 x global_load_dwordx4, hand-issued; ONE vmcnt drain.
    const unsigned long long baseAddr = (unsigned long long)tab;
    const unsigned long long aA = baseAddr + 8ull * (unsigned)idxA;
    const unsigned long long aB = baseAddr + 8ull * (unsigned)idxB;
    const unsigned long long sY  = 8ull * (unsigned)r1;     // +y corner step
    const unsigned long long sX  = 8ull * (unsigned)r1sq;   // +x corner step

    u32x4 eA0, eA1, eA2, eA3, eB0, eB1, eB2, eB3;
    #define GLOAD(dst, addr) \
        asm volatile("global_load_dwordx4 %0, %1, off" : "=&v"(dst) : "v"(addr))
    GLOAD(eA0, aA);
    GLOAD(eA1, aA + sY);
    GLOAD(eA2, aA + sX);
    GLOAD(eA3, aA + sX + sY);
    GLOAD(eB0, aB);
    GLOAD(eB1, aB + sY);
    GLOAD(eB2, aB + sX);
    GLOAD(eB3, aB + sX + sY);
    #undef GLOAD
    // all 8 in flight; single drain. "+v" on every quad so no consumer can be
    // scheduled above the wait (asm-load results aren't compiler-tracked).
    asm volatile("s_waitcnt vmcnt(0)"
                 : "+v"(eA0), "+v"(eA1), "+v"(eA2), "+v"(eA3),
                   "+v"(eB0), "+v"(eB1), "+v"(eB2), "+v"(eB3));
    __builtin_amdgcn_sched_barrier(0);

    const float K = 1.0f / 65536.0f;   // u16 phase -> revolutions

    // e = [p0x|p0y<<16, p0z, p1x|p1y<<16, p1z] (high halves of y/w are zero)
    #define PAIRE(e, WXY, oz_, wz0_, a0, a1, a2, a3, a4, a5)                      \
    {                                                                             \
        const float w0 = (WXY) * (wz0_);                                          \
        const float w1 = (WXY) * (oz_);                                           \
        float sn, cs;                                                             \
        sincos_rev((float)(e.x & 0xffffu) * K, sn, cs); a0 += w0*sn; a3 += w0*cs; \
        sincos_rev((float)(e.x >> 16)     * K, sn, cs); a1 += w0*sn; a4 += w0*cs; \
        sincos_rev((float)(e.y & 0xffffu) * K, sn, cs); a2 += w0*sn; a5 += w0*cs; \
        sincos_rev((float)(e.z & 0xffffu) * K, sn, cs); a0 += w1*sn; a3 += w1*cs; \
        sincos_rev((float)(e.z >> 16)     * K, sn, cs); a1 += w1*sn; a4 += w1*cs; \
        sincos_rev((float)(e.w & 0xffffu) * K, sn, cs); a2 += w1*sn; a5 += w1*cs; \
    }

    float a0 = 0.f, a1 = 0.f, a2 = 0.f, a3 = 0.f, a4 = 0.f, a5 = 0.f;
    {
        const float wz0 = 1.0f - ozA;
        const float wx0 = 1.0f - oxA, wy0 = 1.0f - oyA;
        PAIRE(eA0, wx0 * wy0, ozA, wz0, a0, a1, a2, a3, a4, a5)
        PAIRE(eA1, wx0 * oyA, ozA, wz0, a0, a1, a2, a3, a4, a5)
        PAIRE(eA2, oxA * wy0, ozA, wz0, a0, a1, a2, a3, a4, a5)
        PAIRE(eA3, oxA * oyA, ozA, wz0, a0, a1, a2, a3, a4, a5)
    }
    float b0 = 0.f, b1 = 0.f, b2 = 0.f, b3 = 0.f, b4 = 0.f, b5 = 0.f;
    {
        const float wz0 = 1.0f - ozB;
        const float wx0 = 1.0f - oxB, wy0 = 1.0f - oyB;
        PAIRE(eB0, wx0 * wy0, ozB, wz0, b0, b1, b2, b3, b4, b5)
        PAIRE(eB1, wx0 * oyB, ozB, wz0, b0, b1, b2, b3, b4, b5)
        PAIRE(eB2, oxB * wy0, ozB, wz0, b0, b1, b2, b3, b4, b5)
        PAIRE(eB3, oxB * oyB, ozB, wz0, b0, b1, b2, b3, b4, b5)
    }
    #undef PAIRE

    {
        const int c = 3 + l * 6;
        float* rowA = sres[p];
        rowA[c + 0] = a0; rowA[c + 1] = a1; rowA[c + 2] = a2;
        rowA[c + 3] = a3; rowA[c + 4] = a4; rowA[c + 5] = a5;
        float* rowB = sres[p + 32];
        rowB[c + 0] = b0; rowB[c + 1] = b1; rowB[c + 2] = b2;
        rowB[c + 3] = b3; rowB[c + 4] = b4; rowB[c + 5] = b5;
        if (l == 0) {
            rowA[0] = rxA; rowA[1] = ryA; rowA[2] = rzA;
            rowB[0] = rxB; rowB[1] = ryB; rowB[2] = rzB;
        }
    }
    __syncthreads();

    // coalesced write: 64*51 = 3264 floats = 816 float4 per block (16B aligned)
    if (full_block) {
        const float4* flat4 = (const float4*)&sres[0][0];
        float4* ob4 = (float4*)(out + (size_t)block_base * ROW_F);
        for (int i = tid; i < (PTS_PER_BLOCK * ROW_F) / 4; i += 256)
            ob4[i] = flat4[i];
    } else {
        const float* flat = &sres[0][0];
        float* ob = out + (size_t)block_base * ROW_F;
        const int lim = npts * ROW_F - block_base * ROW_F;
        for (int i = tid; i < PTS_PER_BLOCK * ROW_F; i += 256)
            if (i < lim) ob[i] = flat[i];
    }
}

// ---------------------------------------------------------------------------
// Fallback (ws too small): direct fp32 gather (x4u + x2u), known-good (R3).
// ---------------------------------------------------------------------------
typedef float f4u __attribute__((ext_vector_type(4), aligned(4)));
typedef float f2u __attribute__((ext_vector_type(2), aligned(4)));

__global__ __launch_bounds__(256) void dagrid_kernel_direct(
    const float* __restrict__ xyz,
    const float* __restrict__ data,
    const float* __restrict__ scales,
    const int*   __restrict__ level_offsets,
    const float* __restrict__ bounds,
    float* __restrict__ out,
    int npts)
{
    __shared__ alignas(16) float sxyz[32 * 3];
    __shared__ alignas(16) float sres[32][ROW_F];

    const int tid = threadIdx.x;
    const int l   = tid & 7;
    const int p   = tid >> 3;
    const int block_base = blockIdx.x * 32;

    if (tid < 32 * 3) {
        const int gi = block_base * 3 + tid;
        sxyz[tid] = (gi < npts * 3) ? xyz[gi] : 0.0f;
    }
    const float scale = scales[l];
    const int   off_l = level_offsets[l];
    const float lox = bounds[0], loy = bounds[1], loz = bounds[2];
    const float hix = bounds[3] - 1e-6f;
    const float hiy = bounds[4] - 1e-6f;
    const float hiz = bounds[5] - 1e-6f;
    const float size = fmaxf(fmaxf(bounds[3] - bounds[0], bounds[4] - bounds[1]),
                             bounds[5] - bounds[2]);
    const float inv_size = 1.0f / size;
    __syncthreads();

    const int n = block_base + p;
    const bool active = (n < npts);
    const float rx = sxyz[p * 3 + 0];
    const float ry = sxyz[p * 3 + 1];
    const float rz = sxyz[p * 3 + 2];
    float acc0 = 0.f, acc1 = 0.f, acc2 = 0.f, acc3 = 0.f, acc4 = 0.f, acc5 = 0.f;

    if (active) {
        const float x = fminf(fmaxf(rx, lox), hix);
        const float y = fminf(fmaxf(ry, loy), hiy);
        const float z = fminf(fmaxf(rz, loz), hiz);
        const float xn = (x - lox) * inv_size;
        const float yn = (y - loy) * inv_size;
        const float zn = (z - loz) * inv_size;
        const int r1 = (int)scale + 1;
        const int r1sq = r1 * r1;
        const float fx = xn * scale, fy = yn * scale, fz = zn * scale;
        const float bxf = floorf(fx), byf = floorf(fy), bzf = floorf(fz);
        const float ox = fx - bxf, oy = fy - byf, oz = fz - bzf;
        const int i000 = (int)bxf * r1sq + (int)byf * r1 + (int)bzf + off_l;
        const float* p0 = data + 3 * (size_t)i000;
        const float* p1 = p0 + 3 * r1;
        const float* p2 = p0 + 3 * r1sq;
        const float* p3 = p2 + 3 * r1;
        const f4u q0 = *(const f4u*)p0;  const f2u g0 = *(const f2u*)(p0 + 4);
        const f4u q1 = *(const f4u*)p1;  const f2u g1 = *(const f2u*)(p1 + 4);
        const f4u q2 = *(const f4u*)p2;  const f2u g2 = *(const f2u*)(p2 + 4);
        const f4u q3 = *(const f4u*)p3;  const f2u g3 = *(const f2u*)(p3 + 4);
        const float freq = (float)(1 << l);
        const float wz0 = 1.0f - oz;
        const float wx1 = ox, wx0 = 1.0f - ox;
        const float wy1 = oy, wy0 = 1.0f - oy;
        float sn, cs;
        #define PAIR(a, b, WXY)                                                   \
        {                                                                         \
            const float w0 = (WXY) * wz0;                                         \
            const float w1 = (WXY) * oz;                                          \
            __sincosf(a.x * freq, &sn, &cs); acc0 += w0 * sn; acc3 += w0 * cs;    \
            __sincosf(a.y * freq, &sn, &cs); acc1 += w0 * sn; acc4 += w0 * cs;    \
            __sincosf(a.z * freq, &sn, &cs); acc2 += w0 * sn; acc5 += w0 * cs;    \
            __sincosf(a.w * freq, &sn, &cs); acc0 += w1 * sn; acc3 += w1 * cs;    \
            __sincosf(b.x * freq, &sn, &cs); acc1 += w1 * sn; acc4 += w1 * cs;    \
            __sincosf(b.y * freq, &sn, &cs); acc2 += w1 * sn; acc5 += w1 * cs;    \
        }
        PAIR(q0, g0, wx0 * wy0)
        PAIR(q1, g1, wx0 * wy1)
        PAIR(q2, g2, wx1 * wy0)
        PAIR(q3, g3, wx1 * wy1)
        #undef PAIR
    }
    {
        float* row = sres[p];
        const int c = 3 + l * 6;
        row[c + 0] = acc0; row[c + 1] = acc1; row[c + 2] = acc2;
        row[c + 3] = acc3; row[c + 4] = acc4; row[c + 5] = acc5;
        if (l == 0) { row[0] = rx; row[1] = ry; row[2] = rz; }
    }
    __syncthreads();
    {
        const float* flat = &sres[0][0];
        float* ob = out + (size_t)block_base * ROW_F;
        const int lim = npts * ROW_F - block_base * ROW_F;
        for (int i = tid; i < 32 * ROW_F; i += 256)
            if (i < lim) ob[i] = flat[i];
    }
}

extern "C" void kernel_launch(void* const* d_in, const int* in_sizes, int n_in,
                              void* d_out, int out_size, void* d_ws, size_t ws_size,
                              hipStream_t stream) {
    const float* xyz           = (const float*)d_in[0];
    const float* data          = (const float*)d_in[1];
    const float* scales        = (const float*)d_in[2];
    const int*   level_offsets = (const int*)d_in[3];
    const float* bounds        = (const float*)d_in[4];
    float* out = (float*)d_out;

    const int npts = in_sizes[0] / 3;
    const int T    = in_sizes[1] / 3;

    const size_t ws_needed = (size_t)T * sizeof(uint2);
    if (d_ws != nullptr && ws_size >= ws_needed) {
        uint2* tab = (uint2*)d_ws;
        phase_repack8<<<(T + 255) / 256, 256, 0, stream>>>(data, level_offsets, tab, T);
        const int nblocks = (npts + PTS_PER_BLOCK - 1) / PTS_PER_BLOCK;
        dagrid_kernel<<<nblocks, 256, 0, stream>>>(xyz, tab, scales, level_offsets,
                                                   bounds, out, npts);
    } else {
        const int nblocks = (npts + 31) / 32;
        dagrid_kernel_direct<<<nblocks, 256, 0, stream>>>(xyz, data, scales,
                                                          level_offsets, bounds,
                                                          out, npts);
    }
}